// Round 1
// baseline (983.480 us; speedup 1.0000x reference)
//
#include <hip/hip_runtime.h>
#include <stdint.h>

typedef int i32x4 __attribute__((ext_vector_type(4)));

constexpr int Bb = 2, Ss = 2048, Hh = 1024, NHn = 16;
constexpr int Mm = Bb * Ss;      // 4096 rows
constexpr int BH = Bb * NHn;     // 32 (b,h) pairs
constexpr float CLIPV = 2.5f;

// ---- workspace layout (bytes). scal[0..6]=absmax(h,Wq,Wk,Wv,q,k,v), scal[7]=min rowsum bits
constexpr size_t X8_OFF   = 256;
constexpr size_t W8Q_OFF  = X8_OFF  + (size_t)Mm * Hh;
constexpr size_t W8K_OFF  = W8Q_OFF + (size_t)Hh * Hh;
constexpr size_t W8V_OFF  = W8K_OFF + (size_t)Hh * Hh;
constexpr size_t Q8_OFF   = W8V_OFF + (size_t)Hh * Hh;
constexpr size_t K8_OFF   = Q8_OFF  + (size_t)Mm * Hh;
constexpr size_t V8_OFF   = K8_OFF  + (size_t)Mm * Hh;
constexpr size_t V8T_OFF  = V8_OFF  + (size_t)Mm * Hh;
constexpr size_t RMAX_OFF = V8T_OFF + (size_t)Mm * Hh;
constexpr size_t RSUM_OFF = RMAX_OFF + (size_t)BH * Ss * 4;
// end ~ 23.5 MiB

__device__ __forceinline__ i32x4 zero4() {
  i32x4 z; z[0] = 0; z[1] = 0; z[2] = 0; z[3] = 0; return z;
}

// ---------------- init scalars ----------------
__global__ void k_init(float* scal) {
  if (threadIdx.x < 7) scal[threadIdx.x] = 0.f;
  if (threadIdx.x == 7) ((unsigned int*)scal)[7] = 0x7f800000u;  // +inf
}

// ---------------- abs-max of hidden + 3 weights ----------------
__global__ __launch_bounds__(256) void k_absmax(
    const float* __restrict__ hs, const float* __restrict__ wq,
    const float* __restrict__ wk, const float* __restrict__ wv,
    float* __restrict__ scal) {
  int b = blockIdx.x;
  const float* src; int sidx, boff;
  if (b < 256)      { src = hs; sidx = 0; boff = b; }
  else if (b < 320) { src = wq; sidx = 1; boff = b - 256; }
  else if (b < 384) { src = wk; sidx = 2; boff = b - 320; }
  else              { src = wv; sidx = 3; boff = b - 384; }
  const float4* p = (const float4*)src + (size_t)boff * 4096 + threadIdx.x;
  float m = 0.f;
#pragma unroll
  for (int i = 0; i < 16; ++i) {
    float4 v = p[i * 256];
    m = fmaxf(m, fmaxf(fmaxf(fabsf(v.x), fabsf(v.y)), fmaxf(fabsf(v.z), fabsf(v.w))));
  }
#pragma unroll
  for (int off = 32; off; off >>= 1) m = fmaxf(m, __shfl_xor(m, off));
  __shared__ float red[4];
  if ((threadIdx.x & 63) == 0) red[threadIdx.x >> 6] = m;
  __syncthreads();
  if (threadIdx.x == 0) {
    m = fmaxf(fmaxf(red[0], red[1]), fmaxf(red[2], red[3]));
    atomicMax((unsigned int*)scal + sidx, __float_as_uint(m));
  }
}

// ---------------- quantize hidden + weights to int8 ----------------
__global__ __launch_bounds__(256) void k_quant_in(
    const float* __restrict__ hs, const float* __restrict__ wq,
    const float* __restrict__ wk, const float* __restrict__ wv,
    const float* __restrict__ scal, char* __restrict__ ws) {
  int b = blockIdx.x;
  const float* src; int sidx, boff; unsigned int* dst;
  if (b < 256)      { src = hs; sidx = 0; boff = b;       dst = (unsigned int*)(ws + X8_OFF); }
  else if (b < 320) { src = wq; sidx = 1; boff = b - 256; dst = (unsigned int*)(ws + W8Q_OFF); }
  else if (b < 384) { src = wk; sidx = 2; boff = b - 320; dst = (unsigned int*)(ws + W8K_OFF); }
  else              { src = wv; sidx = 3; boff = b - 384; dst = (unsigned int*)(ws + W8V_OFF); }
  float s = 127.f / fminf(scal[sidx], CLIPV);
  size_t base = (size_t)boff * 4096 + threadIdx.x;
  const float4* p = (const float4*)src + base;
  dst += base;
#pragma unroll
  for (int i = 0; i < 16; ++i) {
    float4 v = p[i * 256];
    int a0 = __float2int_rn(fminf(fmaxf(v.x, -CLIPV), CLIPV) * s);
    int a1 = __float2int_rn(fminf(fmaxf(v.y, -CLIPV), CLIPV) * s);
    int a2 = __float2int_rn(fminf(fmaxf(v.z, -CLIPV), CLIPV) * s);
    int a3 = __float2int_rn(fminf(fmaxf(v.w, -CLIPV), CLIPV) * s);
    dst[i * 256] = (a0 & 255) | ((a1 & 255) << 8) | ((a2 & 255) << 16) | ((a3 & 255) << 24);
  }
}

// ---------------- int8 QKV GEMM: q = x8 @ W8^T * scale + bias ----------------
// grid (16 nblk, 64 mblk, 3 weights), 256 thr. 64x64 tile, 4 waves x 16 rows.
__global__ __launch_bounds__(256) void k_qkv_gemm(
    char* __restrict__ ws, float* __restrict__ qkvf,
    const float* __restrict__ bq, const float* __restrict__ bk,
    const float* __restrict__ bv, const float* __restrict__ scal) {
  int wsel = blockIdx.z;
  const char* a8 = ws + X8_OFF;
  const char* b8 = ws + (wsel == 0 ? W8Q_OFF : wsel == 1 ? W8K_OFF : W8V_OFF);
  const float* bias = wsel == 0 ? bq : wsel == 1 ? bk : bv;
  float* outp = qkvf + (size_t)wsel * Mm * Hh;
  float scaleAB = (fminf(scal[0], CLIPV) / 127.f) * (fminf(scal[1 + wsel], CLIPV) / 127.f);

  __shared__ __align__(16) char lA[64][80];
  __shared__ __align__(16) char lB[64][80];
  int t = threadIdx.x;
  int lane = t & 63, w = t >> 6, c = lane & 15, g = lane >> 4;
  int i0 = blockIdx.y * 64;
  int n0 = blockIdx.x * 64;
  int strow = t >> 2, sto = t & 3;
  int stoff = (sto ^ (strow & 3)) * 16;

  i32x4 acc[4];
#pragma unroll
  for (int nt = 0; nt < 4; ++nt) acc[nt] = zero4();

  for (int kc = 0; kc < 16; ++kc) {
    i32x4 va = *(const i32x4*)(a8 + (size_t)(i0 + strow) * 1024 + kc * 64 + sto * 16);
    i32x4 vb = *(const i32x4*)(b8 + (size_t)(n0 + strow) * 1024 + kc * 64 + sto * 16);
    __syncthreads();
    *(i32x4*)&lA[strow][stoff] = va;
    *(i32x4*)&lB[strow][stoff] = vb;
    __syncthreads();
    i32x4 af = *(const i32x4*)&lA[w * 16 + c][(g ^ (c & 3)) * 16];
#pragma unroll
    for (int nt = 0; nt < 4; ++nt) {
      i32x4 bf = *(const i32x4*)&lB[nt * 16 + c][(g ^ (c & 3)) * 16];
      acc[nt] = __builtin_amdgcn_mfma_i32_16x16x64_i8(af, bf, acc[nt], 0, 0, 0);
    }
  }
  float amax = 0.f;
#pragma unroll
  for (int nt = 0; nt < 4; ++nt) {
    int n = n0 + nt * 16 + c;
    float bvv = bias[n];
#pragma unroll
    for (int r = 0; r < 4; ++r) {
      int i = i0 + w * 16 + g * 4 + r;
      float val = fmaf((float)acc[nt][r], scaleAB, bvv);
      outp[(size_t)i * 1024 + n] = val;
      amax = fmaxf(amax, fabsf(val));
    }
  }
#pragma unroll
  for (int off = 32; off; off >>= 1) amax = fmaxf(amax, __shfl_xor(amax, off));
  if (lane == 0) atomicMax((unsigned int*)scal + 4 + wsel, __float_as_uint(amax));
}

// ---------------- quantize q,k,v fp32 -> int8 ----------------
__global__ __launch_bounds__(256) void k_quant_qkv(
    char* __restrict__ ws, const float* __restrict__ qkvf,
    const float* __restrict__ scal) {
  int b = blockIdx.x;
  int wsel = b >> 8, boff = b & 255;
  const float* src = qkvf + (size_t)wsel * Mm * Hh;
  unsigned int* dst = (unsigned int*)(ws + (wsel == 0 ? Q8_OFF : wsel == 1 ? K8_OFF : V8_OFF));
  float s = 127.f / fminf(scal[4 + wsel], CLIPV);
  size_t base = (size_t)boff * 4096 + threadIdx.x;
  const float4* p = (const float4*)src + base;
  dst += base;
#pragma unroll
  for (int i = 0; i < 16; ++i) {
    float4 v = p[i * 256];
    int a0 = __float2int_rn(fminf(fmaxf(v.x, -CLIPV), CLIPV) * s);
    int a1 = __float2int_rn(fminf(fmaxf(v.y, -CLIPV), CLIPV) * s);
    int a2 = __float2int_rn(fminf(fmaxf(v.z, -CLIPV), CLIPV) * s);
    int a3 = __float2int_rn(fminf(fmaxf(v.w, -CLIPV), CLIPV) * s);
    dst[i * 256] = (a0 & 255) | ((a1 & 255) << 8) | ((a2 & 255) << 16) | ((a3 & 255) << 24);
  }
}

// ---------------- scores = q8@k8^T * scale + mask ; online softmax stats ----------------
// grid (32 iblk, 32 bh), 256 thr. Wave = 16 q-rows. A=K-tile, B=Q-frag (swapped) so each
// lane's 4 acc regs are 4 consecutive j of one q-row -> dwordx4 stores, 64B sectors.
__global__ __launch_bounds__(256) void k_scores(
    const char* __restrict__ ws, const float* __restrict__ mask,
    float* __restrict__ scores, float* __restrict__ rmax,
    float* __restrict__ rsum, const float* __restrict__ scal) {
  const char* q8 = ws + Q8_OFF;
  const char* k8 = ws + K8_OFF;
  int bh = blockIdx.y, b = bh >> 4;
  int h = bh & 15;
  int i0 = blockIdx.x * 64;
  int t = threadIdx.x, lane = t & 63, w = t >> 6, c = lane & 15, g = lane >> 4;
  float scale8 = (fminf(scal[4], CLIPV) / 127.f) * (fminf(scal[5], CLIPV) / 127.f) * 0.125f;

  __shared__ __align__(16) char lK[128][80];

  int irow = i0 + w * 16 + c;
  i32x4 qf = *(const i32x4*)(q8 + (size_t)(b * 2048 + irow) * 1024 + h * 64 + g * 16);
  const float* maskb = mask + b * 2048;
  float* srow_base = scores + ((size_t)bh * 2048 + irow) * 2048;

  float m = -INFINITY, l = 0.f;
  int strow = t >> 2, sto = t & 3;
  int stoff = (sto ^ (strow & 3)) * 16;

  for (int jc = 0; jc < 2048; jc += 128) {
    i32x4 v0 = *(const i32x4*)(k8 + (size_t)(b * 2048 + jc + strow) * 1024 + h * 64 + sto * 16);
    i32x4 v1 = *(const i32x4*)(k8 + (size_t)(b * 2048 + jc + 64 + strow) * 1024 + h * 64 + sto * 16);
    __syncthreads();
    *(i32x4*)&lK[strow][stoff] = v0;
    *(i32x4*)&lK[64 + strow][stoff] = v1;
    __syncthreads();
#pragma unroll
    for (int jt = 0; jt < 8; ++jt) {
      i32x4 kf = *(const i32x4*)&lK[jt * 16 + c][(g ^ (c & 3)) * 16];
      i32x4 d = __builtin_amdgcn_mfma_i32_16x16x64_i8(kf, qf, zero4(), 0, 0, 0);
      int jbase = jc + jt * 16 + g * 4;
      float4 mv = *(const float4*)(maskb + jbase);
      float s0 = fmaf((float)d[0], scale8, mv.x);
      float s1 = fmaf((float)d[1], scale8, mv.y);
      float s2 = fmaf((float)d[2], scale8, mv.z);
      float s3 = fmaf((float)d[3], scale8, mv.w);
      float tmax = fmaxf(fmaxf(s0, s1), fmaxf(s2, s3));
      float mn = fmaxf(m, tmax);
      l = fmaf(l, __expf(m - mn),
               __expf(s0 - mn) + __expf(s1 - mn) + __expf(s2 - mn) + __expf(s3 - mn));
      m = mn;
      float4 outv; outv.x = s0; outv.y = s1; outv.z = s2; outv.w = s3;
      *(float4*)(srow_base + jbase) = outv;
    }
  }
  // combine the 4 g-groups of each q-row (lanes c, c+16, c+32, c+48)
#pragma unroll
  for (int off = 16; off <= 32; off <<= 1) {
    float mo = __shfl_xor(m, off);
    float lo = __shfl_xor(l, off);
    float mn = fmaxf(m, mo);
    l = l * __expf(m - mn) + lo * __expf(mo - mn);
    m = mn;
  }
  if (g == 0) {
    rmax[(size_t)bh * 2048 + irow] = m;
    rsum[(size_t)bh * 2048 + irow] = l;
  }
  float lmin = l;
#pragma unroll
  for (int off = 1; off <= 8; off <<= 1) lmin = fminf(lmin, __shfl_xor(lmin, off));
  if (lane == 0) atomicMin((unsigned int*)scal + 7, __float_as_uint(lmin));
}

// ---------------- transpose v8 [b,j,h,d] -> v8T [b,h,d,j] ----------------
__global__ __launch_bounds__(256) void k_vtrans(char* __restrict__ ws) {
  const char* v8 = ws + V8_OFF;
  char* v8t = ws + V8T_OFF;
  int bh = blockIdx.y, b = bh >> 4, h = bh & 15;
  int jc = blockIdx.x * 64;
  __shared__ __align__(16) char tile[64][80];
  int t = threadIdx.x;
  int j = t >> 2, o = t & 3;
  i32x4 v = *(const i32x4*)(v8 + (size_t)(b * 2048 + jc + j) * 1024 + h * 64 + o * 16);
  *(i32x4*)&tile[j][o * 16] = v;
  __syncthreads();
  int d = t >> 2, seg = t & 3;
  int od[4] = {0, 0, 0, 0};
#pragma unroll
  for (int jj = 0; jj < 16; ++jj)
    od[jj >> 2] |= (int)(unsigned char)tile[seg * 16 + jj][d] << ((jj & 3) * 8);
  i32x4 ov; ov[0] = od[0]; ov[1] = od[1]; ov[2] = od[2]; ov[3] = od[3];
  *(i32x4*)(v8t + ((size_t)bh * 64 + d) * 2048 + jc + seg * 16) = ov;
}

// ---------------- PV: recompute P from int8 q/k, quantize, int8 MFMA with V ----------------
__global__ __launch_bounds__(256) void k_pv(
    char* __restrict__ ws, const float* __restrict__ mask,
    float* __restrict__ ctx, const float* __restrict__ scal) {
  const char* q8 = ws + Q8_OFF;
  const char* k8 = ws + K8_OFF;
  const char* v8t = ws + V8T_OFF;
  const float* rmax = (const float*)(ws + RMAX_OFF);
  const float* rsum = (const float*)(ws + RSUM_OFF);
  int bh = blockIdx.y, b = bh >> 4, h = bh & 15;
  int i0 = blockIdx.x * 64;
  int t = threadIdx.x, lane = t & 63, w = t >> 6, c = lane & 15, g = lane >> 4;
  float scale8 = (fminf(scal[4], CLIPV) / 127.f) * (fminf(scal[5], CLIPV) / 127.f) * 0.125f;
  float min_l = __uint_as_float(((const unsigned int*)scal)[7]);
  float s_p = 127.f * min_l;                       // = 127 / max_prob
  float s_v = 127.f / fminf(scal[6], CLIPV);
  float oscale = 1.f / (s_p * s_v);

  __shared__ __align__(16) char lK[64][80];
  __shared__ __align__(16) int pl[4][16][20];

  int irow = i0 + w * 16 + c;
  i32x4 qf = *(const i32x4*)(q8 + (size_t)(b * 2048 + irow) * 1024 + h * 64 + g * 16);
  float m_i = rmax[(size_t)bh * 2048 + irow];
  float coef = s_p / rsum[(size_t)bh * 2048 + irow];
  const float* maskb = mask + b * 2048;

  i32x4 acc[4];
#pragma unroll
  for (int vt = 0; vt < 4; ++vt) acc[vt] = zero4();

  int strow = t >> 2, sto = t & 3;
  int stoff = (sto ^ (strow & 3)) * 16;

  for (int jc = 0; jc < 2048; jc += 64) {
    i32x4 kv = *(const i32x4*)(k8 + (size_t)(b * 2048 + jc + strow) * 1024 + h * 64 + sto * 16);
    __syncthreads();
    *(i32x4*)&lK[strow][stoff] = kv;
    __syncthreads();
#pragma unroll
    for (int jt = 0; jt < 4; ++jt) {
      i32x4 kf = *(const i32x4*)&lK[jt * 16 + c][(g ^ (c & 3)) * 16];
      i32x4 d = __builtin_amdgcn_mfma_i32_16x16x64_i8(kf, qf, zero4(), 0, 0, 0);
      int jbase = jc + jt * 16 + g * 4;
      float4 mv = *(const float4*)(maskb + jbase);
      float s0 = fmaf((float)d[0], scale8, mv.x);
      float s1 = fmaf((float)d[1], scale8, mv.y);
      float s2 = fmaf((float)d[2], scale8, mv.z);
      float s3 = fmaf((float)d[3], scale8, mv.w);
      int p0 = __float2int_rn(__expf(s0 - m_i) * coef);
      int p1 = __float2int_rn(__expf(s1 - m_i) * coef);
      int p2 = __float2int_rn(__expf(s2 - m_i) * coef);
      int p3 = __float2int_rn(__expf(s3 - m_i) * coef);
      pl[w][c][jt * 4 + g] = (p0 & 255) | ((p1 & 255) << 8) | ((p2 & 255) << 16) | ((p3 & 255) << 24);
    }
    i32x4 pf = *(const i32x4*)&pl[w][c][4 * g];   // A-frag: row c, k bytes g*16..+15
#pragma unroll
    for (int vt = 0; vt < 4; ++vt) {
      i32x4 vf = *(const i32x4*)(v8t + ((size_t)bh * 64 + vt * 16 + c) * 2048 + jc + g * 16);
      acc[vt] = __builtin_amdgcn_mfma_i32_16x16x64_i8(pf, vf, acc[vt], 0, 0, 0);
    }
  }
#pragma unroll
  for (int vt = 0; vt < 4; ++vt) {
#pragma unroll
    for (int r = 0; r < 4; ++r) {
      int i = i0 + w * 16 + g * 4 + r;
      ctx[(size_t)(b * 2048 + i) * 1024 + h * 64 + vt * 16 + c] = (float)acc[vt][r] * oscale;
    }
  }
}

extern "C" void kernel_launch(void* const* d_in, const int* in_sizes, int n_in,
                              void* d_out, int out_size, void* d_ws, size_t ws_size,
                              hipStream_t stream) {
  const float* hs   = (const float*)d_in[0];
  const float* mask = (const float*)d_in[1];
  const float* Wq   = (const float*)d_in[2];
  const float* bq   = (const float*)d_in[3];
  const float* Wk   = (const float*)d_in[4];
  const float* bk   = (const float*)d_in[5];
  const float* Wv   = (const float*)d_in[6];
  const float* bv   = (const float*)d_in[7];
  char* ws = (char*)d_ws;
  float* scal = (float*)ws;
  float* ctx = (float*)d_out;
  float* scores = (float*)d_out + (size_t)Mm * Hh;   // 553MB out: [ctx | scores]
  float* rmax = (float*)(ws + RMAX_OFF);
  float* rsum = (float*)(ws + RSUM_OFF);
  // fp32 q,k,v staged in the (not yet written) scores region of d_out: 48MB << 536MB
  float* qkvf = scores;

  hipLaunchKernelGGL(k_init, dim3(1), dim3(64), 0, stream, scal);
  hipLaunchKernelGGL(k_absmax, dim3(448), dim3(256), 0, stream, hs, Wq, Wk, Wv, scal);
  hipLaunchKernelGGL(k_quant_in, dim3(448), dim3(256), 0, stream, hs, Wq, Wk, Wv, scal, ws);
  hipLaunchKernelGGL(k_qkv_gemm, dim3(16, 64, 3), dim3(256), 0, stream, ws, qkvf, bq, bk, bv, scal);
  hipLaunchKernelGGL(k_quant_qkv, dim3(768), dim3(256), 0, stream, ws, qkvf, scal);
  hipLaunchKernelGGL(k_scores, dim3(32, 32), dim3(256), 0, stream, ws, mask, scores, rmax, rsum, scal);
  hipLaunchKernelGGL(k_vtrans, dim3(32, 32), dim3(256), 0, stream, ws);
  hipLaunchKernelGGL(k_pv, dim3(32, 32), dim3(256), 0, stream, ws, mask, ctx, scal);
}

// Round 7
// 917.568 us; speedup vs baseline: 1.0718x; 1.0718x over previous
//
#include <hip/hip_runtime.h>
#include <stdint.h>

typedef int i32x4 __attribute__((ext_vector_type(4)));
typedef float f32x4 __attribute__((ext_vector_type(4)));

constexpr int Bb = 2, Ss = 2048, Hh = 1024, NHn = 16;
constexpr int Mm = Bb * Ss;      // 4096 rows
constexpr int BH = Bb * NHn;     // 32 (b,h) pairs
constexpr float CLIPV = 2.5f;

// ---- workspace layout (bytes). scal[0..6]=absmax(h,Wq,Wk,Wv,q,k,v), scal[7]=min rowsum bits
constexpr size_t X8_OFF   = 256;
constexpr size_t W8Q_OFF  = X8_OFF  + (size_t)Mm * Hh;
constexpr size_t W8K_OFF  = W8Q_OFF + (size_t)Hh * Hh;
constexpr size_t W8V_OFF  = W8K_OFF + (size_t)Hh * Hh;
constexpr size_t Q8_OFF   = W8V_OFF + (size_t)Hh * Hh;
constexpr size_t K8_OFF   = Q8_OFF  + (size_t)Mm * Hh;
constexpr size_t V8_OFF   = K8_OFF  + (size_t)Mm * Hh;
constexpr size_t V8T_OFF  = V8_OFF  + (size_t)Mm * Hh;
constexpr size_t RMAX_OFF = V8T_OFF + (size_t)Mm * Hh;
constexpr size_t RSUM_OFF = RMAX_OFF + (size_t)BH * Ss * 4;

__device__ __forceinline__ i32x4 zero4() {
  i32x4 z; z[0] = 0; z[1] = 0; z[2] = 0; z[3] = 0; return z;
}

// ---------------- init scalars ----------------
__global__ void k_init(float* scal) {
  if (threadIdx.x < 7) scal[threadIdx.x] = 0.f;
  if (threadIdx.x == 7) ((unsigned int*)scal)[7] = 0x7f800000u;  // +inf
}

// ---------------- abs-max of hidden + 3 weights ----------------
__global__ __launch_bounds__(256) void k_absmax(
    const float* __restrict__ hs, const float* __restrict__ wq,
    const float* __restrict__ wk, const float* __restrict__ wv,
    float* __restrict__ scal) {
  int b = blockIdx.x;
  const float* src; int sidx, boff;
  if (b < 256)      { src = hs; sidx = 0; boff = b; }
  else if (b < 320) { src = wq; sidx = 1; boff = b - 256; }
  else if (b < 384) { src = wk; sidx = 2; boff = b - 320; }
  else              { src = wv; sidx = 3; boff = b - 384; }
  const float4* p = (const float4*)src + (size_t)boff * 4096 + threadIdx.x;
  float m = 0.f;
#pragma unroll
  for (int i = 0; i < 16; ++i) {
    float4 v = p[i * 256];
    m = fmaxf(m, fmaxf(fmaxf(fabsf(v.x), fabsf(v.y)), fmaxf(fabsf(v.z), fabsf(v.w))));
  }
#pragma unroll
  for (int off = 32; off; off >>= 1) m = fmaxf(m, __shfl_xor(m, off));
  __shared__ float red[4];
  if ((threadIdx.x & 63) == 0) red[threadIdx.x >> 6] = m;
  __syncthreads();
  if (threadIdx.x == 0) {
    m = fmaxf(fmaxf(red[0], red[1]), fmaxf(red[2], red[3]));
    atomicMax((unsigned int*)scal + sidx, __float_as_uint(m));
  }
}

// ---------------- quantize hidden + weights to int8 ----------------
__global__ __launch_bounds__(256) void k_quant_in(
    const float* __restrict__ hs, const float* __restrict__ wq,
    const float* __restrict__ wk, const float* __restrict__ wv,
    const float* __restrict__ scal, char* __restrict__ ws) {
  int b = blockIdx.x;
  const float* src; int sidx, boff; unsigned int* dst;
  if (b < 256)      { src = hs; sidx = 0; boff = b;       dst = (unsigned int*)(ws + X8_OFF); }
  else if (b < 320) { src = wq; sidx = 1; boff = b - 256; dst = (unsigned int*)(ws + W8Q_OFF); }
  else if (b < 384) { src = wk; sidx = 2; boff = b - 320; dst = (unsigned int*)(ws + W8K_OFF); }
  else              { src = wv; sidx = 3; boff = b - 384; dst = (unsigned int*)(ws + W8V_OFF); }
  float s = 127.f / fminf(scal[sidx], CLIPV);
  size_t base = (size_t)boff * 4096 + threadIdx.x;
  const float4* p = (const float4*)src + base;
  dst += base;
#pragma unroll
  for (int i = 0; i < 16; ++i) {
    float4 v = p[i * 256];
    int a0 = __float2int_rn(fminf(fmaxf(v.x, -CLIPV), CLIPV) * s);
    int a1 = __float2int_rn(fminf(fmaxf(v.y, -CLIPV), CLIPV) * s);
    int a2 = __float2int_rn(fminf(fmaxf(v.z, -CLIPV), CLIPV) * s);
    int a3 = __float2int_rn(fminf(fmaxf(v.w, -CLIPV), CLIPV) * s);
    dst[i * 256] = (a0 & 255) | ((a1 & 255) << 8) | ((a2 & 255) << 16) | ((a3 & 255) << 24);
  }
}

// ---------------- int8 QKV GEMM: q = x8 @ W8^T * scale + bias ----------------
// 64x64 tile, 4 waves. mfma(bf, af): lane (c,g) reg r -> n = nt*16+g*4+r, i = i0+w*16+c
// => float4 output stores.
__global__ __launch_bounds__(256) void k_qkv_gemm(
    char* __restrict__ ws, float* __restrict__ qkvf,
    const float* __restrict__ bq, const float* __restrict__ bk,
    const float* __restrict__ bv, const float* __restrict__ scal) {
  int wsel = blockIdx.z;
  const char* a8 = ws + X8_OFF;
  const char* b8 = ws + (wsel == 0 ? W8Q_OFF : wsel == 1 ? W8K_OFF : W8V_OFF);
  const float* bias = wsel == 0 ? bq : wsel == 1 ? bk : bv;
  float* outp = qkvf + (size_t)wsel * Mm * Hh;
  float scaleAB = (fminf(scal[0], CLIPV) / 127.f) * (fminf(scal[1 + wsel], CLIPV) / 127.f);

  __shared__ __align__(16) char lA[64][80];
  __shared__ __align__(16) char lB[64][80];
  int t = threadIdx.x;
  int lane = t & 63, w = t >> 6, c = lane & 15, g = lane >> 4;
  int i0 = blockIdx.y * 64;
  int n0 = blockIdx.x * 64;
  int strow = t >> 2, sto = t & 3;
  int stoff = (sto ^ (strow & 3)) * 16;

  i32x4 acc[4];
#pragma unroll
  for (int nt = 0; nt < 4; ++nt) acc[nt] = zero4();

  for (int kc = 0; kc < 16; ++kc) {
    i32x4 va = *(const i32x4*)(a8 + (size_t)(i0 + strow) * 1024 + kc * 64 + sto * 16);
    i32x4 vb = *(const i32x4*)(b8 + (size_t)(n0 + strow) * 1024 + kc * 64 + sto * 16);
    __syncthreads();
    *(i32x4*)&lA[strow][stoff] = va;
    *(i32x4*)&lB[strow][stoff] = vb;
    __syncthreads();
    i32x4 af = *(const i32x4*)&lA[w * 16 + c][(g ^ (c & 3)) * 16];
#pragma unroll
    for (int nt = 0; nt < 4; ++nt) {
      i32x4 bf = *(const i32x4*)&lB[nt * 16 + c][(g ^ (c & 3)) * 16];
      acc[nt] = __builtin_amdgcn_mfma_i32_16x16x64_i8(bf, af, acc[nt], 0, 0, 0);
    }
  }
  int i = i0 + w * 16 + c;
  float amax = 0.f;
#pragma unroll
  for (int nt = 0; nt < 4; ++nt) {
    int n = n0 + nt * 16 + g * 4;
    float4 bv4 = *(const float4*)(bias + n);
    float4 o;
    o.x = fmaf((float)acc[nt][0], scaleAB, bv4.x);
    o.y = fmaf((float)acc[nt][1], scaleAB, bv4.y);
    o.z = fmaf((float)acc[nt][2], scaleAB, bv4.z);
    o.w = fmaf((float)acc[nt][3], scaleAB, bv4.w);
    *(float4*)(outp + (size_t)i * 1024 + n) = o;
    amax = fmaxf(amax, fmaxf(fmaxf(fabsf(o.x), fabsf(o.y)), fmaxf(fabsf(o.z), fabsf(o.w))));
  }
#pragma unroll
  for (int off = 32; off; off >>= 1) amax = fmaxf(amax, __shfl_xor(amax, off));
  if (lane == 0) atomicMax((unsigned int*)scal + 4 + wsel, __float_as_uint(amax));
}

// ---------------- quantize q,k,v fp32 -> int8 ----------------
__global__ __launch_bounds__(256) void k_quant_qkv(
    char* __restrict__ ws, const float* __restrict__ qkvf,
    const float* __restrict__ scal) {
  int b = blockIdx.x;
  int wsel = b >> 8, boff = b & 255;
  const float* src = qkvf + (size_t)wsel * Mm * Hh;
  unsigned int* dst = (unsigned int*)(ws + (wsel == 0 ? Q8_OFF : wsel == 1 ? K8_OFF : V8_OFF));
  float s = 127.f / fminf(scal[4 + wsel], CLIPV);
  size_t base = (size_t)boff * 4096 + threadIdx.x;
  const float4* p = (const float4*)src + base;
  dst += base;
#pragma unroll
  for (int i = 0; i < 16; ++i) {
    float4 v = p[i * 256];
    int a0 = __float2int_rn(fminf(fmaxf(v.x, -CLIPV), CLIPV) * s);
    int a1 = __float2int_rn(fminf(fmaxf(v.y, -CLIPV), CLIPV) * s);
    int a2 = __float2int_rn(fminf(fmaxf(v.z, -CLIPV), CLIPV) * s);
    int a3 = __float2int_rn(fminf(fmaxf(v.w, -CLIPV), CLIPV) * s);
    dst[i * 256] = (a0 & 255) | ((a1 & 255) << 8) | ((a2 & 255) << 16) | ((a3 & 255) << 24);
  }
}

// ---------------- scores = q8@k8^T * scale + mask ; stats ; coalesced nt stores ----
// 1D grid 1024, XCD-grouped. Per-wave LDS transpose of each 16x64 tile -> 1KB/instr stores.
__global__ __launch_bounds__(256) void k_scores(
    const char* __restrict__ ws, const float* __restrict__ mask,
    float* __restrict__ scores, float* __restrict__ rmax,
    float* __restrict__ rsum, const float* __restrict__ scal) {
  const char* q8 = ws + Q8_OFF;
  const char* k8 = ws + K8_OFF;
  int lin = blockIdx.x;
  int swz = (lin & 7) * 128 + (lin >> 3);     // XCD-contiguous: each XCD owns 4 bh slices
  int bh = swz >> 5, iblk = swz & 31;
  int b = bh >> 4, h = bh & 15;
  int i0 = iblk * 64;
  int t = threadIdx.x, lane = t & 63, w = t >> 6, c = lane & 15, g = lane >> 4;
  float scale8 = (fminf(scal[4], CLIPV) / 127.f) * (fminf(scal[5], CLIPV) / 127.f) * 0.125f;

  __shared__ __align__(16) char lK[128][80];
  __shared__ __align__(16) float sbuf[4][16][69];   // per-wave transpose buffer

  int irow = i0 + w * 16 + c;
  i32x4 qf = *(const i32x4*)(q8 + (size_t)(b * 2048 + irow) * 1024 + h * 64 + g * 16);
  const float* maskb = mask + b * 2048;
  float* srow0 = scores + ((size_t)bh * 2048 + i0 + w * 16) * 2048;  // wave's 16 rows

  float m = -INFINITY, l = 0.f;
  int strow = t >> 2, sto = t & 3;
  int stoff = (sto ^ (strow & 3)) * 16;

  for (int jc = 0; jc < 2048; jc += 128) {
    i32x4 v0 = *(const i32x4*)(k8 + (size_t)(b * 2048 + jc + strow) * 1024 + h * 64 + sto * 16);
    i32x4 v1 = *(const i32x4*)(k8 + (size_t)(b * 2048 + jc + 64 + strow) * 1024 + h * 64 + sto * 16);
    __syncthreads();
    *(i32x4*)&lK[strow][stoff] = v0;
    *(i32x4*)&lK[64 + strow][stoff] = v1;
    __syncthreads();
#pragma unroll
    for (int jg = 0; jg < 2; ++jg) {            // two 64-col groups
#pragma unroll
      for (int jtm = 0; jtm < 4; ++jtm) {
        int jt = jg * 4 + jtm;
        i32x4 kf = *(const i32x4*)&lK[jt * 16 + c][(g ^ (c & 3)) * 16];
        i32x4 d = __builtin_amdgcn_mfma_i32_16x16x64_i8(kf, qf, zero4(), 0, 0, 0);
        int jbase = jc + jt * 16 + g * 4;
        float4 mv = *(const float4*)(maskb + jbase);
        float s0 = fmaf((float)d[0], scale8, mv.x);
        float s1 = fmaf((float)d[1], scale8, mv.y);
        float s2 = fmaf((float)d[2], scale8, mv.z);
        float s3 = fmaf((float)d[3], scale8, mv.w);
        float tmax = fmaxf(fmaxf(s0, s1), fmaxf(s2, s3));
        float mn = fmaxf(m, tmax);
        l = fmaf(l, __expf(m - mn),
                 __expf(s0 - mn) + __expf(s1 - mn) + __expf(s2 - mn) + __expf(s3 - mn));
        m = mn;
        float* sp = &sbuf[w][c][jtm * 16 + g * 4];
        sp[0] = s0; sp[1] = s1; sp[2] = s2; sp[3] = s3;
      }
      // wave-local transpose read + coalesced nontemporal store (no barrier needed)
      int h4 = lane >> 4, k2 = (lane & 15) * 4;
#pragma unroll
      for (int rr = 0; rr < 4; ++rr) {
        int row = rr * 4 + h4;
        f32x4 val = *(const f32x4*)&sbuf[w][row][k2];
        __builtin_nontemporal_store(val,
            (f32x4*)(srow0 + (size_t)row * 2048 + jc + jg * 64 + k2));
      }
    }
  }
  // combine the 4 g-groups of each q-row (lanes c, c+16, c+32, c+48)
#pragma unroll
  for (int off = 16; off <= 32; off <<= 1) {
    float mo = __shfl_xor(m, off);
    float lo = __shfl_xor(l, off);
    float mn = fmaxf(m, mo);
    l = l * __expf(m - mn) + lo * __expf(mo - mn);
    m = mn;
  }
  if (g == 0) {
    rmax[(size_t)bh * 2048 + irow] = m;
    rsum[(size_t)bh * 2048 + irow] = l;
  }
  float lmin = l;
#pragma unroll
  for (int off = 1; off <= 8; off <<= 1) lmin = fminf(lmin, __shfl_xor(lmin, off));
  if (lane == 0) atomicMin((unsigned int*)scal + 7, __float_as_uint(lmin));
}

// ---------------- transpose v8 [b,j,h,d] -> v8T [b,h,d,j] ----------------
__global__ __launch_bounds__(256) void k_vtrans(char* __restrict__ ws) {
  const char* v8 = ws + V8_OFF;
  char* v8t = ws + V8T_OFF;
  int bh = blockIdx.y, b = bh >> 4, h = bh & 15;
  int jc = blockIdx.x * 64;
  __shared__ __align__(16) char tile[64][80];
  int t = threadIdx.x;
  int j = t >> 2, o = t & 3;
  i32x4 v = *(const i32x4*)(v8 + (size_t)(b * 2048 + jc + j) * 1024 + h * 64 + o * 16);
  *(i32x4*)&tile[j][o * 16] = v;
  __syncthreads();
  int d = t >> 2, seg = t & 3;
  int od[4] = {0, 0, 0, 0};
#pragma unroll
  for (int jj = 0; jj < 16; ++jj)
    od[jj >> 2] |= (int)(unsigned char)tile[seg * 16 + jj][d] << ((jj & 3) * 8);
  i32x4 ov; ov[0] = od[0]; ov[1] = od[1]; ov[2] = od[2]; ov[3] = od[3];
  *(i32x4*)(v8t + ((size_t)bh * 64 + d) * 2048 + jc + seg * 16) = ov;
}

// ---------------- PV: recompute P from int8 q/k, quantize, int8 MFMA with V ----------------
// mfma(vf, pf): lane (c,g) reg r -> d = vt*16+g*4+r, i = i0+w*16+c  => float4 ctx stores.
__global__ __launch_bounds__(256) void k_pv(
    char* __restrict__ ws, const float* __restrict__ mask,
    float* __restrict__ ctx, const float* __restrict__ scal) {
  const char* q8 = ws + Q8_OFF;
  const char* k8 = ws + K8_OFF;
  const char* v8t = ws + V8T_OFF;
  const float* rmax = (const float*)(ws + RMAX_OFF);
  const float* rsum = (const float*)(ws + RSUM_OFF);
  int lin = blockIdx.x;
  int swz = (lin & 7) * 128 + (lin >> 3);
  int bh = swz >> 5, iblk = swz & 31;
  int b = bh >> 4, h = bh & 15;
  int i0 = iblk * 64;
  int t = threadIdx.x, lane = t & 63, w = t >> 6, c = lane & 15, g = lane >> 4;
  float scale8 = (fminf(scal[4], CLIPV) / 127.f) * (fminf(scal[5], CLIPV) / 127.f) * 0.125f;
  float min_l = __uint_as_float(((const unsigned int*)scal)[7]);
  float s_p = 127.f * min_l;                       // = 127 / max_prob
  float s_v = 127.f / fminf(scal[6], CLIPV);
  float oscale = 1.f / (s_p * s_v);

  __shared__ __align__(16) char lK[64][80];
  __shared__ __align__(16) int pl[4][16][20];

  int irow = i0 + w * 16 + c;
  i32x4 qf = *(const i32x4*)(q8 + (size_t)(b * 2048 + irow) * 1024 + h * 64 + g * 16);
  float m_i = rmax[(size_t)bh * 2048 + irow];
  float coef = s_p / rsum[(size_t)bh * 2048 + irow];
  const float* maskb = mask + b * 2048;

  i32x4 acc[4];
#pragma unroll
  for (int vt = 0; vt < 4; ++vt) acc[vt] = zero4();

  int strow = t >> 2, sto = t & 3;
  int stoff = (sto ^ (strow & 3)) * 16;

  for (int jc = 0; jc < 2048; jc += 64) {
    i32x4 kv = *(const i32x4*)(k8 + (size_t)(b * 2048 + jc + strow) * 1024 + h * 64 + sto * 16);
    __syncthreads();
    *(i32x4*)&lK[strow][stoff] = kv;
    __syncthreads();
#pragma unroll
    for (int jt = 0; jt < 4; ++jt) {
      i32x4 kf = *(const i32x4*)&lK[jt * 16 + c][(g ^ (c & 3)) * 16];
      i32x4 d = __builtin_amdgcn_mfma_i32_16x16x64_i8(kf, qf, zero4(), 0, 0, 0);
      int jbase = jc + jt * 16 + g * 4;
      float4 mv = *(const float4*)(maskb + jbase);
      float s0 = fmaf((float)d[0], scale8, mv.x);
      float s1 = fmaf((float)d[1], scale8, mv.y);
      float s2 = fmaf((float)d[2], scale8, mv.z);
      float s3 = fmaf((float)d[3], scale8, mv.w);
      int p0 = __float2int_rn(__expf(s0 - m_i) * coef);
      int p1 = __float2int_rn(__expf(s1 - m_i) * coef);
      int p2 = __float2int_rn(__expf(s2 - m_i) * coef);
      int p3 = __float2int_rn(__expf(s3 - m_i) * coef);
      pl[w][c][jt * 4 + g] = (p0 & 255) | ((p1 & 255) << 8) | ((p2 & 255) << 16) | ((p3 & 255) << 24);
    }
    i32x4 pf = *(const i32x4*)&pl[w][c][4 * g];   // A/B-frag: row c, k bytes g*16..+15
#pragma unroll
    for (int vt = 0; vt < 4; ++vt) {
      i32x4 vf = *(const i32x4*)(v8t + ((size_t)bh * 64 + vt * 16 + c) * 2048 + jc + g * 16);
      acc[vt] = __builtin_amdgcn_mfma_i32_16x16x64_i8(vf, pf, acc[vt], 0, 0, 0);
    }
  }
  int i = i0 + w * 16 + c;
#pragma unroll
  for (int vt = 0; vt < 4; ++vt) {
    f32x4 o;
    o[0] = (float)acc[vt][0] * oscale;
    o[1] = (float)acc[vt][1] * oscale;
    o[2] = (float)acc[vt][2] * oscale;
    o[3] = (float)acc[vt][3] * oscale;
    __builtin_nontemporal_store(o,
        (f32x4*)(ctx + (size_t)(b * 2048 + i) * 1024 + h * 64 + vt * 16 + g * 4));
  }
}

extern "C" void kernel_launch(void* const* d_in, const int* in_sizes, int n_in,
                              void* d_out, int out_size, void* d_ws, size_t ws_size,
                              hipStream_t stream) {
  const float* hs   = (const float*)d_in[0];
  const float* mask = (const float*)d_in[1];
  const float* Wq   = (const float*)d_in[2];
  const float* bq   = (const float*)d_in[3];
  const float* Wk   = (const float*)d_in[4];
  const float* bk   = (const float*)d_in[5];
  const float* Wv   = (const float*)d_in[6];
  const float* bv   = (const float*)d_in[7];
  char* ws = (char*)d_ws;
  float* scal = (float*)ws;
  float* ctx = (float*)d_out;
  float* scores = (float*)d_out + (size_t)Mm * Hh;   // 553MB out: [ctx | scores]
  float* rmax = (float*)(ws + RMAX_OFF);
  float* rsum = (float*)(ws + RSUM_OFF);
  // fp32 q,k,v staged in the (not yet written) scores region of d_out
  float* qkvf = scores;

  hipLaunchKernelGGL(k_init, dim3(1), dim3(64), 0, stream, scal);
  hipLaunchKernelGGL(k_absmax, dim3(448), dim3(256), 0, stream, hs, Wq, Wk, Wv, scal);
  hipLaunchKernelGGL(k_quant_in, dim3(448), dim3(256), 0, stream, hs, Wq, Wk, Wv, scal, ws);
  hipLaunchKernelGGL(k_qkv_gemm, dim3(16, 64, 3), dim3(256), 0, stream, ws, qkvf, bq, bk, bv, scal);
  hipLaunchKernelGGL(k_quant_qkv, dim3(768), dim3(256), 0, stream, ws, qkvf, scal);
  hipLaunchKernelGGL(k_scores, dim3(1024), dim3(256), 0, stream, ws, mask, scores, rmax, rsum, scal);
  hipLaunchKernelGGL(k_vtrans, dim3(32, 32), dim3(256), 0, stream, ws);
  hipLaunchKernelGGL(k_pv, dim3(1024), dim3(256), 0, stream, ws, mask, ctx, scal);
}